// Round 5
// baseline (9.927 us; speedup 1.0000x reference)
//
#include <hip/hip_runtime.h>

typedef float vfloat2 __attribute__((ext_vector_type(2)));

// out[row, :] = weight[ids[row], :]
// rows = B*L = 8192, D = 128 floats = 64 float2 per row.
// One full wave (64 lanes) per row; each lane moves one float2.
// 8192 waves = 32/CU = full occupancy -> max independent id->gather chains.
// Non-temporal store: output is write-once, never re-read -> don't pollute
// L2 (keeps weight rows resident for the gather).
__global__ __launch_bounds__(256) void soft_embedding_gather(
        const int* __restrict__ ids,
        const vfloat2* __restrict__ w2,
        vfloat2* __restrict__ out2,
        int n_rows) {
    const int gid = blockIdx.x * blockDim.x + threadIdx.x;
    const int row = gid >> 6;       // 64 threads (one wave) per row
    const int c   = gid & 63;       // float2 index within row (D/2 = 64)
    if (row >= n_rows) return;
    const int id = ids[row];        // wave-uniform
    const vfloat2 v = w2[(size_t)id * 64 + c];
    __builtin_nontemporal_store(v, &out2[(size_t)row * 64 + c]);
}

extern "C" void kernel_launch(void* const* d_in, const int* in_sizes, int n_in,
                              void* d_out, int out_size, void* d_ws, size_t ws_size,
                              hipStream_t stream) {
    const int*   ids = (const int*)d_in[0];     // [B*L] = 8192
    const float* w   = (const float*)d_in[1];   // [32000, 128]
    float*       out = (float*)d_out;           // [B*L, 128]

    const int n_rows = in_sizes[0];             // 8192
    const int total  = n_rows * 64;             // threads: 64 per row
    const int block  = 256;
    const int grid   = (total + block - 1) / block;   // 2048 blocks

    soft_embedding_gather<<<grid, block, 0, stream>>>(
        ids, (const vfloat2*)w, (vfloat2*)out, n_rows);
}